// Round 2
// baseline (5741.385 us; speedup 1.0000x reference)
//
#include <hip/hip_runtime.h>

#define BSZ 32
#define T 1024
#define D 512
#define H 512

// Recurrent weight residency split: k in [0, 2*NPAIR_REG) lives in per-thread
// VGPRs (packed f16 pairs); k in [2*NPAIR_REG, 512) lives in LDS.
// 184 pairs -> 184 VGPRs of weights; LDS part = 72*512*4 B = 144 KB.
#define NPAIR_REG 184
#define NPAIR_LDS 72
#define KREG (2 * NPAIR_REG)

typedef _Float16 h2v __attribute__((ext_vector_type(2)));
union U32H2 { unsigned int u; h2v h; };

__device__ __forceinline__ unsigned int pack2(float x, float y) {
  U32H2 c; c.h = h2v{(_Float16)x, (_Float16)y}; return c.u;
}
__device__ __forceinline__ h2v uph(unsigned int u) { U32H2 c; c.u = u; return c.h; }

#if defined(__has_builtin)
#if __has_builtin(__builtin_amdgcn_fdot2)
#define HAVE_FDOT2 1
#endif
#endif

__device__ __forceinline__ float fdot2f(unsigned int w, unsigned int h, float acc) {
#ifdef HAVE_FDOT2
  return __builtin_amdgcn_fdot2(uph(w), uph(h), acc, false);
#else
  h2v wv = uph(w), hv = uph(h);
  acc = fmaf((float)wv[0], (float)hv[0], acc);
  return fmaf((float)wv[1], (float)hv[1], acc);
#endif
}

// ---------------------------------------------------------------------------
// Projection GEMM: C[m][n] = sum_d A[m][d] * W[n][d]
// A: [M x 512] row-major, W: [512 x 512] row-major (PyTorch w_ih layout), fp32.
// 64x64 tile, BK=32, 256 threads, 4x4 micro-tile per thread.
// ---------------------------------------------------------------------------
#define BM 64
#define BN 64
#define BK 32

__global__ __launch_bounds__(256) void gemm_proj(const float* __restrict__ A,
                                                 const float* __restrict__ W,
                                                 float* __restrict__ C) {
  __shared__ float As[BK][BM + 4];
  __shared__ float Bs[BK][BN + 4];
  const int bn = blockIdx.x * BN;
  const int bm = blockIdx.y * BM;
  const int tid = threadIdx.x;
  const int tx = tid & 15;
  const int ty = tid >> 4;
  float acc[4][4] = {};

  for (int k0 = 0; k0 < D; k0 += BK) {
    const int c = tid & 31;   // k offset within tile
    const int r0 = tid >> 5;  // row offset (8 rows per pass)
    #pragma unroll
    for (int i = 0; i < 8; ++i) {
      const int r = r0 + i * 8;
      As[c][r] = A[(size_t)(bm + r) * D + (k0 + c)];
      Bs[c][r] = W[(size_t)(bn + r) * D + (k0 + c)];
    }
    __syncthreads();
    #pragma unroll
    for (int kk = 0; kk < BK; ++kk) {
      const float4 av = *(const float4*)&As[kk][ty * 4];
      const float4 bv = *(const float4*)&Bs[kk][tx * 4];
      acc[0][0] = fmaf(av.x, bv.x, acc[0][0]);
      acc[0][1] = fmaf(av.x, bv.y, acc[0][1]);
      acc[0][2] = fmaf(av.x, bv.z, acc[0][2]);
      acc[0][3] = fmaf(av.x, bv.w, acc[0][3]);
      acc[1][0] = fmaf(av.y, bv.x, acc[1][0]);
      acc[1][1] = fmaf(av.y, bv.y, acc[1][1]);
      acc[1][2] = fmaf(av.y, bv.z, acc[1][2]);
      acc[1][3] = fmaf(av.y, bv.w, acc[1][3]);
      acc[2][0] = fmaf(av.z, bv.x, acc[2][0]);
      acc[2][1] = fmaf(av.z, bv.y, acc[2][1]);
      acc[2][2] = fmaf(av.z, bv.z, acc[2][2]);
      acc[2][3] = fmaf(av.z, bv.w, acc[2][3]);
      acc[3][0] = fmaf(av.w, bv.x, acc[3][0]);
      acc[3][1] = fmaf(av.w, bv.y, acc[3][1]);
      acc[3][2] = fmaf(av.w, bv.z, acc[3][2]);
      acc[3][3] = fmaf(av.w, bv.w, acc[3][3]);
    }
    __syncthreads();
  }
  #pragma unroll
  for (int i = 0; i < 4; ++i) {
    float4 o;
    o.x = acc[i][0]; o.y = acc[i][1]; o.z = acc[i][2]; o.w = acc[i][3];
    *(float4*)&C[(size_t)(bm + ty * 4 + i) * H + (bn + tx * 4)] = o;
  }
}

// ---------------------------------------------------------------------------
// Recurrence: one workgroup per batch element. h = tanh(Z[t] + bias + Whh·h).
// Thread j owns output j; W row j resident as packed f16: 184 pairs in VGPRs,
// 72 pairs in LDS. h kept double-buffered in LDS as f16 pairs (broadcast reads).
// ---------------------------------------------------------------------------
__global__ __launch_bounds__(512, 2) void rnn_rec(const float* __restrict__ Z,
                                                  const float* __restrict__ Whh,
                                                  const float* __restrict__ b_ih,
                                                  const float* __restrict__ b_hh,
                                                  float* __restrict__ Y,
                                                  float* __restrict__ Hlast) {
  const int b = blockIdx.x;
  const int j = threadIdx.x;
  __shared__ __align__(16) unsigned int h2[2][H / 2];       // 2 KB
  __shared__ unsigned int wl[NPAIR_LDS][H];                 // 144 KB

  // Pack W[j][0..KREG) into registers (static indices only -> stays in VGPRs).
  unsigned int wreg[NPAIR_REG];
  const float* wrow = Whh + (size_t)j * H;
  #pragma unroll
  for (int i = 0; i < NPAIR_REG; ++i) {
    const float2 w = *(const float2*)(wrow + 2 * i);
    wreg[i] = pack2(w.x, w.y);
  }
  // LDS-resident tail of W: wl[p][j] = pack(W[j][KREG+2p], W[j][KREG+2p+1]).
  #pragma unroll 4
  for (int p = 0; p < NPAIR_LDS; ++p) {
    const float2 w = *(const float2*)(wrow + KREG + 2 * p);
    wl[p][j] = pack2(w.x, w.y);
  }
  const float biasj = b_ih[j] + b_hh[j];
  if (j < H / 2) h2[0][j] = 0u;
  __syncthreads();

  const float* zb = Z + (size_t)b * T * H;
  float* yb = Y + (size_t)b * T * H;
  float hn = 0.0f;

  #pragma unroll 1
  for (int t = 0; t < T; ++t) {
    const float zt = zb[(size_t)t * H + j];  // issued early, consumed at end
    const uint4* hq4 = (const uint4*)h2[t & 1];
    // 4 independent accumulator chains to hide v_dot2 latency.
    float a0 = 0.f, a1 = 0.f, a2 = 0.f, a3 = 0.f;
    #pragma unroll
    for (int i4 = 0; i4 < NPAIR_REG / 4; ++i4) {  // 46 iters: 1 b128 bcast + 4 dot2
      const uint4 hq = hq4[i4];
      a0 = fdot2f(wreg[4 * i4 + 0], hq.x, a0);
      a1 = fdot2f(wreg[4 * i4 + 1], hq.y, a1);
      a2 = fdot2f(wreg[4 * i4 + 2], hq.z, a2);
      a3 = fdot2f(wreg[4 * i4 + 3], hq.w, a3);
    }
    #pragma unroll
    for (int p4 = 0; p4 < NPAIR_LDS / 4; ++p4) {  // 18 iters
      const uint4 hq = hq4[NPAIR_REG / 4 + p4];
      a0 = fdot2f(wl[4 * p4 + 0][j], hq.x, a0);
      a1 = fdot2f(wl[4 * p4 + 1][j], hq.y, a1);
      a2 = fdot2f(wl[4 * p4 + 2][j], hq.z, a2);
      a3 = fdot2f(wl[4 * p4 + 3][j], hq.w, a3);
    }
    const float pre = zt + biasj + ((a0 + a1) + (a2 + a3));
    // tanh(x) = 1 - 2/(e^{2x}+1); exact at saturation, ~1e-7 rel elsewhere.
    const float e = __expf(2.0f * pre);
    hn = 1.0f - 2.0f / (e + 1.0f);
    // Write next h buffer (other buffer than the one being read this step).
    ((_Float16*)h2[(t + 1) & 1])[j] = (_Float16)hn;
    yb[(size_t)t * H + j] = hn;
    __syncthreads();
  }
  Hlast[(size_t)b * H + j] = hn;
}

// ---------------------------------------------------------------------------
extern "C" void kernel_launch(void* const* d_in, const int* in_sizes, int n_in,
                              void* d_out, int out_size, void* d_ws, size_t ws_size,
                              hipStream_t stream) {
  const float* x     = (const float*)d_in[0];
  const float* w_ih0 = (const float*)d_in[1];
  const float* w_hh0 = (const float*)d_in[2];
  const float* b_ih0 = (const float*)d_in[3];
  const float* b_hh0 = (const float*)d_in[4];
  const float* w_ih1 = (const float*)d_in[5];
  const float* w_hh1 = (const float*)d_in[6];
  const float* b_ih1 = (const float*)d_in[7];
  const float* b_hh1 = (const float*)d_in[8];

  float* out = (float*)d_out;
  float* Y  = out;                                  // y1 region [B*T*H]
  float* HL = out + (size_t)BSZ * T * H;            // hidden [2][B][H]
  float* Z  = (float*)d_ws;                         // scratch pre-activations [B*T*H]

  const dim3 ggrid(H / BN, (BSZ * T) / BM);         // (8, 512)

  // Layer 0: Z = x @ w_ih0^T ; recurrence -> y0 (stored in d_out y region)
  gemm_proj<<<ggrid, 256, 0, stream>>>(x, w_ih0, Z);
  rnn_rec<<<BSZ, 512, 0, stream>>>(Z, w_hh0, b_ih0, b_hh0, Y, HL);

  // Layer 1: Z = y0 @ w_ih1^T ; recurrence overwrites y region with y1
  gemm_proj<<<ggrid, 256, 0, stream>>>(Y, w_ih1, Z);
  rnn_rec<<<BSZ, 512, 0, stream>>>(Z, w_hh1, b_ih1, b_hh1, Y, HL + (size_t)BSZ * H);
}

// Round 3
// 4881.334 us; speedup vs baseline: 1.1762x; 1.1762x over previous
//
#include <hip/hip_runtime.h>

#define BSZ 32
#define T 1024
#define D 512
#define H 512

// Recurrent weight residency: k in [0, 368) lives in per-thread VGPRs as six
// ext_vector_type(32) SSA values (W0..W5, 184 packed f16 pairs, literal-index
// access ONLY -- a plain array gets left in scratch by PromoteAlloca, which is
// exactly what round-2 counters showed: VGPR=128, +10MB spill writes).
// k in [368, 512) lives in LDS as uint2 rows (ds_read_b64).
#define NPAIR_REG 184
#define NPAIR_LDS 72
#define KREG (2 * NPAIR_REG)       // 368
#define NLROW (NPAIR_LDS / 2)      // 36 uint2 rows

typedef _Float16 h2v __attribute__((ext_vector_type(2)));
typedef unsigned int u32x32 __attribute__((ext_vector_type(32)));
union U32H2 { unsigned int u; h2v h; };

__device__ __forceinline__ unsigned int pack2(float x, float y) {
  U32H2 c; c.h = h2v{(_Float16)x, (_Float16)y}; return c.u;
}
__device__ __forceinline__ h2v uph(unsigned int u) { U32H2 c; c.u = u; return c.h; }

#if defined(__has_builtin)
#if __has_builtin(__builtin_amdgcn_fdot2)
#define HAVE_FDOT2 1
#endif
#endif

__device__ __forceinline__ float fdot2f(unsigned int w, unsigned int h, float acc) {
#ifdef HAVE_FDOT2
  return __builtin_amdgcn_fdot2(uph(w), uph(h), acc, false);
#else
  h2v wv = uph(w), hv = uph(h);
  acc = fmaf((float)wv[0], (float)hv[0], acc);
  return fmaf((float)wv[1], (float)hv[1], acc);
#endif
}

// ---------------------------------------------------------------------------
// Projection GEMM: C[m][n] = sum_d A[m][d] * W[n][d]   (fp32, 64x64 tile)
// ---------------------------------------------------------------------------
#define BM 64
#define BN 64
#define BK 32

__global__ __launch_bounds__(256) void gemm_proj(const float* __restrict__ A,
                                                 const float* __restrict__ W,
                                                 float* __restrict__ C) {
  __shared__ float As[BK][BM + 4];
  __shared__ float Bs[BK][BN + 4];
  const int bn = blockIdx.x * BN;
  const int bm = blockIdx.y * BM;
  const int tid = threadIdx.x;
  const int tx = tid & 15;
  const int ty = tid >> 4;
  float acc[4][4] = {};

  for (int k0 = 0; k0 < D; k0 += BK) {
    const int c = tid & 31;
    const int r0 = tid >> 5;
    #pragma unroll
    for (int i = 0; i < 8; ++i) {
      const int r = r0 + i * 8;
      As[c][r] = A[(size_t)(bm + r) * D + (k0 + c)];
      Bs[c][r] = W[(size_t)(bn + r) * D + (k0 + c)];
    }
    __syncthreads();
    #pragma unroll
    for (int kk = 0; kk < BK; ++kk) {
      const float4 av = *(const float4*)&As[kk][ty * 4];
      const float4 bv = *(const float4*)&Bs[kk][tx * 4];
      acc[0][0] = fmaf(av.x, bv.x, acc[0][0]);
      acc[0][1] = fmaf(av.x, bv.y, acc[0][1]);
      acc[0][2] = fmaf(av.x, bv.z, acc[0][2]);
      acc[0][3] = fmaf(av.x, bv.w, acc[0][3]);
      acc[1][0] = fmaf(av.y, bv.x, acc[1][0]);
      acc[1][1] = fmaf(av.y, bv.y, acc[1][1]);
      acc[1][2] = fmaf(av.y, bv.z, acc[1][2]);
      acc[1][3] = fmaf(av.y, bv.w, acc[1][3]);
      acc[2][0] = fmaf(av.z, bv.x, acc[2][0]);
      acc[2][1] = fmaf(av.z, bv.y, acc[2][1]);
      acc[2][2] = fmaf(av.z, bv.z, acc[2][2]);
      acc[2][3] = fmaf(av.z, bv.w, acc[2][3]);
      acc[3][0] = fmaf(av.w, bv.x, acc[3][0]);
      acc[3][1] = fmaf(av.w, bv.y, acc[3][1]);
      acc[3][2] = fmaf(av.w, bv.z, acc[3][2]);
      acc[3][3] = fmaf(av.w, bv.w, acc[3][3]);
    }
    __syncthreads();
  }
  #pragma unroll
  for (int i = 0; i < 4; ++i) {
    float4 o;
    o.x = acc[i][0]; o.y = acc[i][1]; o.z = acc[i][2]; o.w = acc[i][3];
    *(float4*)&C[(size_t)(bm + ty * 4 + i) * H + (bn + tx * 4)] = o;
  }
}

// -------- literal-index weight macros (NEVER variable-subscript a vector) ---
#define LDW2(V, k, off) { const float4 w_ = *(const float4*)(wrow + (off)); \
  V[k] = pack2(w_.x, w_.y); V[(k)+1] = pack2(w_.z, w_.w); }

#define LDV32(V, fb) \
  LDW2(V,0,(fb)+0)  LDW2(V,2,(fb)+4)  LDW2(V,4,(fb)+8)  LDW2(V,6,(fb)+12) \
  LDW2(V,8,(fb)+16) LDW2(V,10,(fb)+20) LDW2(V,12,(fb)+24) LDW2(V,14,(fb)+28) \
  LDW2(V,16,(fb)+32) LDW2(V,18,(fb)+36) LDW2(V,20,(fb)+40) LDW2(V,22,(fb)+44) \
  LDW2(V,24,(fb)+48) LDW2(V,26,(fb)+52) LDW2(V,28,(fb)+56) LDW2(V,30,(fb)+60)

#define DOTG(V, k0, g) { const uint4 hq_ = hq4[(g)]; \
  a0 = fdot2f(V[(k0)+0], hq_.x, a0); a1 = fdot2f(V[(k0)+1], hq_.y, a1); \
  a2 = fdot2f(V[(k0)+2], hq_.z, a2); a3 = fdot2f(V[(k0)+3], hq_.w, a3); }

#define DOTV32(V, gb) \
  DOTG(V,0,(gb))   DOTG(V,4,(gb)+1)  DOTG(V,8,(gb)+2)  DOTG(V,12,(gb)+3) \
  DOTG(V,16,(gb)+4) DOTG(V,20,(gb)+5) DOTG(V,24,(gb)+6) DOTG(V,28,(gb)+7)

// ---------------------------------------------------------------------------
// Recurrence: one WG per batch. h = tanh(Z[t] + bias + Whh·h).
// Thread j owns output j. W row j: 184 f16 pairs in VGPRs, 72 in LDS.
// h double-buffered in LDS as f16 pairs (uniform-address b128 broadcasts).
// ---------------------------------------------------------------------------
__global__ __launch_bounds__(512, 2) void rnn_rec(const float* __restrict__ Z,
                                                  const float* __restrict__ Whh,
                                                  const float* __restrict__ b_ih,
                                                  const float* __restrict__ b_hh,
                                                  float* __restrict__ Y,
                                                  float* __restrict__ Hlast) {
  const int b = blockIdx.x;
  const int j = threadIdx.x;
  __shared__ __align__(16) unsigned int h2[2][H / 2];  // 2 KB
  __shared__ uint2 wl2[NLROW][H];                      // 36*512*8 = 144 KB

  const float* wrow = Whh + (size_t)j * H;

  u32x32 W0, W1, W2, W3, W4, W5;
  LDV32(W0, 0) LDV32(W1, 64) LDV32(W2, 128) LDV32(W3, 192) LDV32(W4, 256)
  LDW2(W5, 0, 320) LDW2(W5, 2, 324) LDW2(W5, 4, 328) LDW2(W5, 6, 332)
  LDW2(W5, 8, 336) LDW2(W5, 10, 340) LDW2(W5, 12, 344) LDW2(W5, 14, 348)
  LDW2(W5, 16, 352) LDW2(W5, 18, 356) LDW2(W5, 20, 360) LDW2(W5, 22, 364)

  // LDS tail: wl2[p][j] = pairs (KREG+4p .. KREG+4p+3) of row j.
  #pragma unroll 4
  for (int p = 0; p < NLROW; ++p) {
    const float4 w = *(const float4*)(wrow + KREG + 4 * p);
    wl2[p][j] = make_uint2(pack2(w.x, w.y), pack2(w.z, w.w));
  }
  const float biasj = b_ih[j] + b_hh[j];
  if (j < H / 2) h2[0][j] = 0u;
  __syncthreads();

  const float* zb = Z + (size_t)b * T * H;
  float* yb = Y + (size_t)b * T * H;
  float hn = 0.0f;

  #pragma unroll 1
  for (int t = 0; t < T; ++t) {
    const float zt = zb[(size_t)t * H + j];  // issued first, consumed last
    const uint4* hq4 = (const uint4*)h2[t & 1];
    float a0 = 0.f, a1 = 0.f, a2 = 0.f, a3 = 0.f;
    // Register-resident part: 46 groups x {1 b128 broadcast + 4 v_dot2}.
    DOTV32(W0, 0) DOTV32(W1, 8) DOTV32(W2, 16) DOTV32(W3, 24) DOTV32(W4, 32)
    DOTG(W5, 0, 40) DOTG(W5, 4, 41) DOTG(W5, 8, 42)
    DOTG(W5, 12, 43) DOTG(W5, 16, 44) DOTG(W5, 20, 45)
    // LDS-resident tail: 18 groups x {1 b128 bcast + 2 b64 + 4 v_dot2}.
    #pragma unroll
    for (int g = 0; g < 18; ++g) {
      const uint4 hq = hq4[46 + g];
      const uint2 wa = wl2[2 * g][j];
      const uint2 wb = wl2[2 * g + 1][j];
      a0 = fdot2f(wa.x, hq.x, a0);
      a1 = fdot2f(wa.y, hq.y, a1);
      a2 = fdot2f(wb.x, hq.z, a2);
      a3 = fdot2f(wb.y, hq.w, a3);
    }
    const float pre = zt + biasj + ((a0 + a1) + (a2 + a3));
    // tanh(x) = 1 - 2/(e^{2x}+1); exact at saturation.
    const float e = __expf(2.0f * pre);
    hn = 1.0f - 2.0f / (e + 1.0f);
    ((_Float16*)h2[(t + 1) & 1])[j] = (_Float16)hn;
    yb[(size_t)t * H + j] = hn;
    __syncthreads();
  }
  Hlast[(size_t)b * H + j] = hn;
}

// ---------------------------------------------------------------------------
extern "C" void kernel_launch(void* const* d_in, const int* in_sizes, int n_in,
                              void* d_out, int out_size, void* d_ws, size_t ws_size,
                              hipStream_t stream) {
  const float* x     = (const float*)d_in[0];
  const float* w_ih0 = (const float*)d_in[1];
  const float* w_hh0 = (const float*)d_in[2];
  const float* b_ih0 = (const float*)d_in[3];
  const float* b_hh0 = (const float*)d_in[4];
  const float* w_ih1 = (const float*)d_in[5];
  const float* w_hh1 = (const float*)d_in[6];
  const float* b_ih1 = (const float*)d_in[7];
  const float* b_hh1 = (const float*)d_in[8];

  float* out = (float*)d_out;
  float* Y  = out;                                  // y1 region [B*T*H]
  float* HL = out + (size_t)BSZ * T * H;            // hidden [2][B][H]
  float* Z  = (float*)d_ws;                         // scratch pre-activations

  const dim3 ggrid(H / BN, (BSZ * T) / BM);         // (8, 512)

  gemm_proj<<<ggrid, 256, 0, stream>>>(x, w_ih0, Z);
  rnn_rec<<<BSZ, 512, 0, stream>>>(Z, w_hh0, b_ih0, b_hh0, Y, HL);

  gemm_proj<<<ggrid, 256, 0, stream>>>(Y, w_ih1, Z);
  rnn_rec<<<BSZ, 512, 0, stream>>>(Z, w_hh1, b_ih1, b_hh1, Y, HL + (size_t)BSZ * H);
}

// Round 4
// 4011.963 us; speedup vs baseline: 1.4311x; 1.2167x over previous
//
#include <hip/hip_runtime.h>

#define BSZ 32
#define T 1024
#define D 512
#define H 512

// K-split recurrence: 1024 threads/WG; thread (j,s) owns output j's half-dot
// over columns [s*256, s*256+256) = 128 f16 pairs. 23 uint4 groups (92 pairs)
// live in VGPRs (4-reg tuples, literal element access only), 9 groups (36
// pairs) in LDS. Per-thread live-set ~115 < the 128-VGPR hard cap a
// 1024-thread block imposes -> no spill (round-3 failure mode: 512 threads
// needed 220 live, allocator targeted 128 and spilled; WRITE_SIZE +8.7MB).
#define NG_REG 23
#define NG_LDS 9

typedef _Float16 h2v __attribute__((ext_vector_type(2)));
union U32H2 { unsigned int u; h2v h; };

__device__ __forceinline__ unsigned int pack2(float x, float y) {
  U32H2 c; c.h = h2v{(_Float16)x, (_Float16)y}; return c.u;
}
__device__ __forceinline__ h2v uph(unsigned int u) { U32H2 c; c.u = u; return c.h; }

#if defined(__has_builtin)
#if __has_builtin(__builtin_amdgcn_fdot2)
#define HAVE_FDOT2 1
#endif
#endif

__device__ __forceinline__ float fdot2f(unsigned int w, unsigned int h, float acc) {
#ifdef HAVE_FDOT2
  return __builtin_amdgcn_fdot2(uph(w), uph(h), acc, false);
#else
  h2v wv = uph(w), hv = uph(h);
  acc = fmaf((float)wv[0], (float)hv[0], acc);
  return fmaf((float)wv[1], (float)hv[1], acc);
#endif
}

// ---------------------------------------------------------------------------
// Projection GEMM: C[m][n] = sum_d A[m][d] * W[n][d]   (fp32, 64x64 tile)
// ---------------------------------------------------------------------------
#define BM 64
#define BN 64
#define BK 32

__global__ __launch_bounds__(256) void gemm_proj(const float* __restrict__ A,
                                                 const float* __restrict__ W,
                                                 float* __restrict__ C) {
  __shared__ float As[BK][BM + 4];
  __shared__ float Bs[BK][BN + 4];
  const int bn = blockIdx.x * BN;
  const int bm = blockIdx.y * BM;
  const int tid = threadIdx.x;
  const int tx = tid & 15;
  const int ty = tid >> 4;
  float acc[4][4] = {};

  for (int k0 = 0; k0 < D; k0 += BK) {
    const int c = tid & 31;
    const int r0 = tid >> 5;
    #pragma unroll
    for (int i = 0; i < 8; ++i) {
      const int r = r0 + i * 8;
      As[c][r] = A[(size_t)(bm + r) * D + (k0 + c)];
      Bs[c][r] = W[(size_t)(bn + r) * D + (k0 + c)];
    }
    __syncthreads();
    #pragma unroll
    for (int kk = 0; kk < BK; ++kk) {
      const float4 av = *(const float4*)&As[kk][ty * 4];
      const float4 bv = *(const float4*)&Bs[kk][tx * 4];
      acc[0][0] = fmaf(av.x, bv.x, acc[0][0]);
      acc[0][1] = fmaf(av.x, bv.y, acc[0][1]);
      acc[0][2] = fmaf(av.x, bv.z, acc[0][2]);
      acc[0][3] = fmaf(av.x, bv.w, acc[0][3]);
      acc[1][0] = fmaf(av.y, bv.x, acc[1][0]);
      acc[1][1] = fmaf(av.y, bv.y, acc[1][1]);
      acc[1][2] = fmaf(av.y, bv.z, acc[1][2]);
      acc[1][3] = fmaf(av.y, bv.w, acc[1][3]);
      acc[2][0] = fmaf(av.z, bv.x, acc[2][0]);
      acc[2][1] = fmaf(av.z, bv.y, acc[2][1]);
      acc[2][2] = fmaf(av.z, bv.z, acc[2][2]);
      acc[2][3] = fmaf(av.z, bv.w, acc[2][3]);
      acc[3][0] = fmaf(av.w, bv.x, acc[3][0]);
      acc[3][1] = fmaf(av.w, bv.y, acc[3][1]);
      acc[3][2] = fmaf(av.w, bv.z, acc[3][2]);
      acc[3][3] = fmaf(av.w, bv.w, acc[3][3]);
    }
    __syncthreads();
  }
  #pragma unroll
  for (int i = 0; i < 4; ++i) {
    float4 o;
    o.x = acc[i][0]; o.y = acc[i][1]; o.z = acc[i][2]; o.w = acc[i][3];
    *(float4*)&C[(size_t)(bm + ty * 4 + i) * H + (bn + tx * 4)] = o;
  }
}

// --- per-group weight macros: named uint4 SSA values, literal fields only ---
#define DECLW(n) uint4 W##n;
#define LOADW(n, g) { \
  const float4 wa_ = *(const float4*)(wrow + cb + 8 * (g)); \
  const float4 wb_ = *(const float4*)(wrow + cb + 8 * (g) + 4); \
  W##n.x = pack2(wa_.x, wa_.y); W##n.y = pack2(wa_.z, wa_.w); \
  W##n.z = pack2(wb_.x, wb_.y); W##n.w = pack2(wb_.z, wb_.w); }
#define DOTW(n, g) { const uint4 hq_ = hq4[(g)]; \
  a0 = fdot2f(W##n.x, hq_.x, a0); a1 = fdot2f(W##n.y, hq_.y, a1); \
  a2 = fdot2f(W##n.z, hq_.z, a2); a3 = fdot2f(W##n.w, hq_.w, a3); }

#define ALLW(M) \
  M(00,0) M(01,1) M(02,2) M(03,3) M(04,4) M(05,5) M(06,6) M(07,7) \
  M(08,8) M(09,9) M(10,10) M(11,11) M(12,12) M(13,13) M(14,14) M(15,15) \
  M(16,16) M(17,17) M(18,18) M(19,19) M(20,20) M(21,21) M(22,22)
#define DECLW_M(n, g) DECLW(n)

// ---------------------------------------------------------------------------
// Recurrence: one WG (1024 thr) per batch. h = tanh(Z[t] + bias + Whh·h).
// Thread (j = tid&511, s = tid>>9): partial dot over columns [s*256, s*256+256).
// s=1 writes partial to LDS; s=0 combines, tanh, writes h & y.
// ---------------------------------------------------------------------------
__global__ __launch_bounds__(1024, 4) __attribute__((amdgpu_waves_per_eu(4, 4)))
void rnn_rec(const float* __restrict__ Z,
             const float* __restrict__ Whh,
             const float* __restrict__ b_ih,
             const float* __restrict__ b_hh,
             float* __restrict__ Y,
             float* __restrict__ Hlast) {
  const int b = blockIdx.x;
  const int tid = threadIdx.x;
  const int j = tid & (H - 1);
  const int s = tid >> 9;

  __shared__ __align__(16) unsigned int h2[2][H / 2];  // 2 KB (f16 pairs)
  __shared__ uint4 wl4[NG_LDS][1024];                  // 9*1024*16 = 144 KB
  __shared__ float part[H];                            // 2 KB

  const float* wrow = Whh + (size_t)j * H;
  const int cb = s << 8;  // column base of this thread's half

  ALLW(DECLW_M)
  ALLW(LOADW)

  // LDS tail: groups NG_REG..NG_REG+8 of this thread's half.
  #pragma unroll
  for (int q = 0; q < NG_LDS; ++q) {
    const int g = NG_REG + q;
    const float4 wa = *(const float4*)(wrow + cb + 8 * g);
    const float4 wb = *(const float4*)(wrow + cb + 8 * g + 4);
    uint4 wv;
    wv.x = pack2(wa.x, wa.y); wv.y = pack2(wa.z, wa.w);
    wv.z = pack2(wb.x, wb.y); wv.w = pack2(wb.z, wb.w);
    wl4[q][tid] = wv;
  }
  const float biasj = b_ih[j] + b_hh[j];
  if (tid < H / 2) h2[0][tid] = 0u;
  __syncthreads();

  const float* zb = Z + (size_t)b * T * H;
  float* yb = Y + (size_t)b * T * H;
  float hn = 0.0f;

  #pragma unroll 1
  for (int t = 0; t < T; ++t) {
    float zt = 0.0f;
    if (s == 0) zt = zb[(size_t)t * H + j];  // wave-uniform branch
    const uint4* hq4 = ((const uint4*)h2[t & 1]) + (s << 5);
    float a0 = 0.f, a1 = 0.f, a2 = 0.f, a3 = 0.f;
    // Register-resident: 23 groups x {1 uniform b128 bcast + 4 v_dot2}.
    ALLW(DOTW)
    // LDS-resident: 9 groups x {1 b128 (per-lane) + 1 b128 bcast + 4 v_dot2}.
    #pragma unroll
    for (int q = 0; q < NG_LDS; ++q) {
      const uint4 wv = wl4[q][tid];
      const uint4 hq = hq4[NG_REG + q];
      a0 = fdot2f(wv.x, hq.x, a0);
      a1 = fdot2f(wv.y, hq.y, a1);
      a2 = fdot2f(wv.z, hq.z, a2);
      a3 = fdot2f(wv.w, hq.w, a3);
    }
    const float asum = (a0 + a1) + (a2 + a3);
    if (s == 1) part[j] = asum;
    __syncthreads();
    if (s == 0) {
      const float pre = zt + biasj + asum + part[j];
      // tanh(x) = 1 - 2/(e^{2x}+1); exact at saturation.
      const float e = __expf(2.0f * pre);
      hn = 1.0f - 2.0f / (e + 1.0f);
      ((_Float16*)h2[(t + 1) & 1])[j] = (_Float16)hn;
      yb[(size_t)t * H + j] = hn;
    }
    __syncthreads();
  }
  if (s == 0) Hlast[(size_t)b * H + j] = hn;
}

// ---------------------------------------------------------------------------
extern "C" void kernel_launch(void* const* d_in, const int* in_sizes, int n_in,
                              void* d_out, int out_size, void* d_ws, size_t ws_size,
                              hipStream_t stream) {
  const float* x     = (const float*)d_in[0];
  const float* w_ih0 = (const float*)d_in[1];
  const float* w_hh0 = (const float*)d_in[2];
  const float* b_ih0 = (const float*)d_in[3];
  const float* b_hh0 = (const float*)d_in[4];
  const float* w_ih1 = (const float*)d_in[5];
  const float* w_hh1 = (const float*)d_in[6];
  const float* b_ih1 = (const float*)d_in[7];
  const float* b_hh1 = (const float*)d_in[8];

  float* out = (float*)d_out;
  float* Y  = out;                                  // y1 region [B*T*H]
  float* HL = out + (size_t)BSZ * T * H;            // hidden [2][B][H]
  float* Z  = (float*)d_ws;                         // scratch pre-activations

  const dim3 ggrid(H / BN, (BSZ * T) / BM);         // (8, 512)

  gemm_proj<<<ggrid, 256, 0, stream>>>(x, w_ih0, Z);
  rnn_rec<<<BSZ, 1024, 0, stream>>>(Z, w_hh0, b_ih0, b_hh0, Y, HL);

  gemm_proj<<<ggrid, 256, 0, stream>>>(Y, w_ih1, Z);
  rnn_rec<<<BSZ, 1024, 0, stream>>>(Z, w_hh1, b_ih1, b_hh1, Y, HL + (size_t)BSZ * H);
}